// Round 15
// baseline (85.405 us; speedup 1.0000x reference)
//
#include <hip/hip_runtime.h>

#define NN 4096
#define FIN 256
#define CC 256
#define NH 8
#define NW32 (NN / 32)  // u32 words per adj row

typedef __attribute__((ext_vector_type(8))) short short8;
typedef __attribute__((ext_vector_type(4))) float f32x4;
typedef __attribute__((ext_vector_type(4))) unsigned int u32x4;

__device__ __forceinline__ unsigned cvtpk_bf16(float lo, float hi) {
  unsigned r;
  asm("v_cvt_pk_bf16_f32 %0, %1, %2" : "=v"(r) : "v"(lo), "v"(hi));
  return r;
}

__device__ __forceinline__ unsigned short bf16rn(float x) {
  unsigned int u = __builtin_bit_cast(unsigned int, x);
  u += 0x7fffu + ((u >> 16) & 1u);
  return (unsigned short)(u >> 16);
}

__device__ __forceinline__ void gl_lds16(const void* g, void* l) {
  __builtin_amdgcn_global_load_lds(
      (const __attribute__((address_space(1))) void*)g,
      (__attribute__((address_space(3))) void*)l, 16, 0, 0);
}

// ---------------- K1: fused {GEMM+epilogue | adj bitpack} by block range ---
// blocks [0,512): GEMM g=h@W -> swizzled gTs + spack + dtc.
// blocks [512, 512+2048): bitpack (one u32 word per thread, 8x int4 stream).
// adjb[i][w] bit e = adj[i][w*32+e]!=0.
// gTs: chunk-major SWIZZLED bf16 (16B unit at [jc][c][p], p = q ^ ((c>>1)&3)).
// spack[h][n] = (e^s_src, e^{0.2 s_src}, 0, 0).
// dtc[h][jc][plane][32] = (e^sd, e^{0.2 sd}).
#define GROWS 8
#define GEMM_BLKS (NN / GROWS)                  // 512
#define BP_BLKS (NN * NW32 / 256)               // 2048
__global__ __launch_bounds__(256) void k_gemm(
    const float* __restrict__ h, const float* __restrict__ W,
    const float* __restrict__ a, const int* __restrict__ adj,
    unsigned int* __restrict__ adjb, unsigned short* __restrict__ gTs,
    float4* __restrict__ spack, float* __restrict__ dtc) {
  __shared__ float hs[GROWS][FIN];
  const int t = threadIdx.x;
  const int bx = blockIdx.x;

  if (bx >= GEMM_BLKS) {
    const int wid = (bx - GEMM_BLKS) * 256 + t;  // word index
    const int row = wid >> 7, wd = wid & 127;
    const int* src = adj + (size_t)row * NN + wd * 32;
    int4 v[8];
#pragma unroll
    for (int s = 0; s < 8; ++s) v[s] = *(const int4*)&src[s * 4];
    unsigned int bits = 0;
#pragma unroll
    for (int s = 0; s < 8; ++s) {
      bits |= (v[s].x ? 1u : 0u) << (s * 4 + 0);
      bits |= (v[s].y ? 1u : 0u) << (s * 4 + 1);
      bits |= (v[s].z ? 1u : 0u) << (s * 4 + 2);
      bits |= (v[s].w ? 1u : 0u) << (s * 4 + 3);
    }
    adjb[(size_t)row * NW32 + wd] = bits;
    return;
  }

  // ---- GEMM path ----
  const int r0 = bx * GROWS;
#pragma unroll
  for (int idx = t; idx < GROWS * FIN / 4; idx += 256) {
    const int r = idx >> 6, c4 = idx & 63;
    *(float4*)&hs[r][c4 * 4] =
        *(const float4*)&h[(size_t)(r0 + r) * FIN + c4 * 4];
  }
  __syncthreads();
  const int c = t;
  float acc[GROWS];
#pragma unroll
  for (int r = 0; r < GROWS; ++r) acc[r] = 0.f;
  for (int k = 0; k < FIN; k += 4) {
    const float w0 = W[(size_t)(k + 0) * CC + c];
    const float w1 = W[(size_t)(k + 1) * CC + c];
    const float w2 = W[(size_t)(k + 2) * CC + c];
    const float w3 = W[(size_t)(k + 3) * CC + c];
#pragma unroll
    for (int r = 0; r < GROWS; ++r) {
      const float4 hv = *(const float4*)&hs[r][k];
      acc[r] += hv.x * w0 + hv.y * w1 + hv.z * w2 + hv.w * w3;
    }
  }
  const int f = c & 31, hh = c >> 5;
  const float aS = a[f], aD = a[32 + f];
  unsigned short gu[GROWS];
#pragma unroll
  for (int r = 0; r < GROWS; ++r) {
    float ps = acc[r] * aS, pd = acc[r] * aD;
#pragma unroll
    for (int m = 1; m < 32; m <<= 1) {
      ps += __shfl_xor(ps, m, 64);
      pd += __shfl_xor(pd, m, 64);
    }
    if (f == 0) {
      const int n = r0 + r;
      spack[(size_t)hh * NN + n] =
          make_float4(__expf(ps), __expf(0.2f * ps), 0.f, 0.f);
      float* dc = dtc + ((size_t)hh * (NN / 32) + (n >> 5)) * 64 + (n & 31);
      dc[0] = __expf(pd);
      dc[32] = __expf(0.2f * pd);
    }
    gu[r] = bf16rn(acc[r]);
  }
  uint4 gv;
  gv.x = (unsigned)gu[0] | ((unsigned)gu[1] << 16);
  gv.y = (unsigned)gu[2] | ((unsigned)gu[3] << 16);
  gv.z = (unsigned)gu[4] | ((unsigned)gu[5] << 16);
  gv.w = (unsigned)gu[6] | ((unsigned)gu[7] << 16);
  const int jc = r0 >> 5, qq = (r0 >> 3) & 3;
  const int p = qq ^ ((c >> 1) & 3);
  *(uint4*)(gTs + ((size_t)jc * 1024 + c * 4 + p) * 8) = gv;
}

// ---------------- K2: in-block j-split, barrier-free j-loop, tree-reduce ---
// Block = 32 i x 1 head; 4 waves, wave w owns j-quarter [w*1024, w*1024+1024).
// Wave-private LDS staging (gl_lds, vmcnt-fenced, NO __syncthreads in loop).
// Final cross-wave sum via LDS tree (3 barriers). Output written directly.
// e^leaky(ss+sd) = max(e^ss*e^sd, e^{0.2ss}*e^{0.2sd})  (exact identity).
__global__ __launch_bounds__(256, 3) void k_attn(
    const unsigned int* __restrict__ adjb, const unsigned short* __restrict__ gTs,
    const float4* __restrict__ spack, const float* __restrict__ dtc,
    float* __restrict__ out) {
  __shared__ unsigned short gt_lds[4][2][1024];  // 16 KB: per-wave dbuf, 2KB ea
  __shared__ float red[2][2][3][4][64];          // 12 KB reduce scratch

  const int lane = threadIdx.x & 63;
  const int w = threadIdx.x >> 6;
  const int il = lane & 15, q = lane >> 4;
  const int bx = blockIdx.x;
  const int hh = bx & 7;        // head -> XCD-pinned via %8 round-robin
  const int ib = bx >> 3;
  const int i0 = ib * 32;
  const int jc0 = w * 32;       // this wave's first 32-j chunk (of 128 total)

  // hoisted i-side scalars
  float e1v[2], e2v[2];
#pragma unroll
  for (int it = 0; it < 2; ++it) {
    const float4 v = spack[(size_t)hh * NN + i0 + it * 16 + il];
    e1v[it] = v.x; e2v[it] = v.y;
  }

  f32x4 acc[2][2];
  f32x4 lac[2];
#pragma unroll
  for (int it = 0; it < 2; ++it) {
#pragma unroll
    for (int r = 0; r < 4; ++r) lac[it][r] = 0.f;
#pragma unroll
    for (int ft = 0; ft < 2; ++ft)
#pragma unroll
      for (int r = 0; r < 4; ++r) acc[it][ft][r] = 0.f;
  }

  const short8 ones = {(short)0x3F80, (short)0x3F80, (short)0x3F80,
                       (short)0x3F80, (short)0x3F80, (short)0x3F80,
                       (short)0x3F80, (short)0x3F80};

  const unsigned int* abr0 = adjb + (size_t)(i0 + il) * NW32 + jc0;
  const unsigned int* abr1 = adjb + (size_t)(i0 + 16 + il) * NW32 + jc0;
  const float* dbase = dtc + (size_t)hh * (NN / 32) * 64 + (size_t)jc0 * 64;
  const int sh = q * 8;
  const int u0 = il * 4 + (q ^ ((il >> 1) & 3));  // swizzled B-frag unit

  // wave-private staging: one 32-j chunk = 128 x 16B units (2 gl_lds)
  auto stage = [&](int buf, int jc) {
    const unsigned short* src = gTs + ((size_t)(jc0 + jc) * 1024 + hh * 128) * 8;
    char* dst = (char*)&gt_lds[w][buf][0];
    gl_lds16(src + (size_t)lane * 8, dst);
    gl_lds16(src + (size_t)(64 + lane) * 8, dst + 1024);
  };

  // prologue: chunk 0 in flight
  stage(0, 0);
  unsigned int pb0 = abr0[0], pb1 = abr1[0];
  float4 pd0 = *(const float4*)(dbase + q * 8);
  float4 pd1 = *(const float4*)(dbase + q * 8 + 4);
  float4 pd2 = *(const float4*)(dbase + 32 + q * 8);
  float4 pd3 = *(const float4*)(dbase + 32 + q * 8 + 4);
  int cur = 0;

  for (int jc = 0; jc < 32; ++jc) {
    // wave-private fence: previous stage complete (issued one phase ago)
    asm volatile("s_waitcnt vmcnt(0)" ::: "memory");
    __builtin_amdgcn_sched_barrier(0);
    if (jc + 1 < 32) stage(cur ^ 1, jc + 1);

    const unsigned int bits0 = pb0, bits1 = pb1;
    float e1j[8], e2j[8];
    *(float4*)&e1j[0] = pd0; *(float4*)&e1j[4] = pd1;
    *(float4*)&e2j[0] = pd2; *(float4*)&e2j[4] = pd3;
    if (jc + 1 < 32) {
      pb0 = abr0[jc + 1];
      pb1 = abr1[jc + 1];
      const float* dp = dbase + (size_t)(jc + 1) * 64;
      pd0 = *(const float4*)(dp + q * 8);
      pd1 = *(const float4*)(dp + q * 8 + 4);
      pd2 = *(const float4*)(dp + 32 + q * 8);
      pd3 = *(const float4*)(dp + 32 + q * 8 + 4);
    }

    const short8 b0 = *(const short8*)&gt_lds[w][cur][u0 * 8];
    const short8 b1 = *(const short8*)&gt_lds[w][cur][(u0 + 64) * 8];
#pragma unroll
    for (int it = 0; it < 2; ++it) {
      const unsigned int bits = it ? bits1 : bits0;
      const float ei1 = e1v[it], ei2 = e2v[it];
      float wv[8];
#pragma unroll
      for (int e = 0; e < 8; ++e)
        wv[e] = ((bits >> (sh + e)) & 1u)
                    ? fmaxf(ei1 * e1j[e], ei2 * e2j[e])
                    : 0.f;
      u32x4 uu;
#pragma unroll
      for (int m = 0; m < 4; ++m) uu[m] = cvtpk_bf16(wv[2 * m], wv[2 * m + 1]);
      const short8 afr = __builtin_bit_cast(short8, uu);
      acc[it][0] = __builtin_amdgcn_mfma_f32_16x16x32_bf16(afr, b0, acc[it][0],
                                                           0, 0, 0);
      acc[it][1] = __builtin_amdgcn_mfma_f32_16x16x32_bf16(afr, b1, acc[it][1],
                                                           0, 0, 0);
      lac[it] = __builtin_amdgcn_mfma_f32_16x16x32_bf16(afr, ones, lac[it], 0,
                                                        0, 0);
    }
    cur ^= 1;
  }

  // ---- cross-wave tree reduction (j-quarters -> full j sum) ----
  if (w >= 2) {
    const int s = w - 2;
#pragma unroll
    for (int it = 0; it < 2; ++it)
#pragma unroll
      for (int r = 0; r < 4; ++r) {
        red[s][it][0][r][lane] = acc[it][0][r];
        red[s][it][1][r][lane] = acc[it][1][r];
        red[s][it][2][r][lane] = lac[it][r];
      }
  }
  __syncthreads();
  if (w < 2) {
#pragma unroll
    for (int it = 0; it < 2; ++it)
#pragma unroll
      for (int r = 0; r < 4; ++r) {
        acc[it][0][r] += red[w][it][0][r][lane];
        acc[it][1][r] += red[w][it][1][r][lane];
        lac[it][r] += red[w][it][2][r][lane];
      }
  }
  __syncthreads();
  if (w == 1) {
#pragma unroll
    for (int it = 0; it < 2; ++it)
#pragma unroll
      for (int r = 0; r < 4; ++r) {
        red[0][it][0][r][lane] = acc[it][0][r];
        red[0][it][1][r][lane] = acc[it][1][r];
        red[0][it][2][r][lane] = lac[it][r];
      }
  }
  __syncthreads();
  if (w == 0) {
#pragma unroll
    for (int it = 0; it < 2; ++it)
#pragma unroll
      for (int r = 0; r < 4; ++r) {
        const float a0 = acc[it][0][r] + red[0][it][0][r][lane];
        const float a1 = acc[it][1][r] + red[0][it][1][r][lane];
        const float lsum = lac[it][r] + red[0][it][2][r][lane];
        const float inv = 1.f / lsum;
        const size_t irow = i0 + it * 16 + q * 4 + r;
        out[irow * CC + hh * 32 + il] = a0 * inv;
        out[irow * CC + hh * 32 + 16 + il] = a1 * inv;
      }
  }
}

extern "C" void kernel_launch(void* const* d_in, const int* in_sizes, int n_in,
                              void* d_out, int out_size, void* d_ws,
                              size_t ws_size, hipStream_t stream) {
  (void)in_sizes; (void)n_in; (void)out_size; (void)ws_size;
  const float* h = (const float*)d_in[0];
  const int* adj = (const int*)d_in[1];
  const float* W = (const float*)d_in[2];
  const float* a = (const float*)d_in[3];
  float* out = (float*)d_out;
  char* ws = (char*)d_ws;

  unsigned short* gTs = (unsigned short*)ws;               // 2 MB (swizzled)
  float4* spack = (float4*)(ws + (size_t)NN * CC * 2);     // 512 KB
  float* dtc = (float*)(spack + (size_t)NH * NN);          // 256 KB
  unsigned int* adjb =
      (unsigned int*)(dtc + (size_t)NH * (NN / 32) * 64);  // 2 MB

  k_gemm<<<GEMM_BLKS + BP_BLKS, 256, 0, stream>>>(h, W, a, adj, adjb, gTs,
                                                  spack, dtc);
  k_attn<<<(NN / 32) * NH, 256, 0, stream>>>(adjb, gTs, spack, dtc, out);
}

// Round 16
// 76.493 us; speedup vs baseline: 1.1165x; 1.1165x over previous
//
#include <hip/hip_runtime.h>

#define NN 4096
#define FIN 256
#define CC 256
#define NH 8
#define NW32 (NN / 32)  // u32 words per adj row

typedef __attribute__((ext_vector_type(8))) short short8;
typedef __attribute__((ext_vector_type(4))) float f32x4;
typedef __attribute__((ext_vector_type(4))) unsigned int u32x4;

__device__ __forceinline__ unsigned cvtpk_bf16(float lo, float hi) {
  unsigned r;
  asm("v_cvt_pk_bf16_f32 %0, %1, %2" : "=v"(r) : "v"(lo), "v"(hi));
  return r;
}

__device__ __forceinline__ unsigned short bf16rn(float x) {
  unsigned int u = __builtin_bit_cast(unsigned int, x);
  u += 0x7fffu + ((u >> 16) & 1u);
  return (unsigned short)(u >> 16);
}

__device__ __forceinline__ void gl_lds16(const void* g, void* l) {
  __builtin_amdgcn_global_load_lds(
      (const __attribute__((address_space(1))) void*)g,
      (__attribute__((address_space(3))) void*)l, 16, 0, 0);
}

// ---------------- K1: fused {GEMM+epilogue | adj bitpack} by block range ---
// blocks [0,512): GEMM g=h@W -> swizzled gTs + spack + dtc.
// blocks [512, 512+2048): bitpack (one u32 word per thread, 8x int4 stream).
// adjb[i][w] bit e = adj[i][w*32+e]!=0.
// gTs: chunk-major SWIZZLED bf16 (16B unit at [jc][c][p], p = q ^ ((c>>1)&3)).
// spack[h][n] = (e^s_src, e^{0.2 s_src}, 0, 0).
// dtc[h][jc][plane][32] = (e^sd, e^{0.2 sd}).
#define GROWS 8
#define GEMM_BLKS (NN / GROWS)                  // 512
#define BP_BLKS (NN * NW32 / 256)               // 2048
__global__ __launch_bounds__(256) void k_gemm(
    const float* __restrict__ h, const float* __restrict__ W,
    const float* __restrict__ a, const int* __restrict__ adj,
    unsigned int* __restrict__ adjb, unsigned short* __restrict__ gTs,
    float4* __restrict__ spack, float* __restrict__ dtc) {
  __shared__ float hs[GROWS][FIN];
  const int t = threadIdx.x;
  const int bx = blockIdx.x;

  if (bx >= GEMM_BLKS) {
    const int wid = (bx - GEMM_BLKS) * 256 + t;  // word index
    const int row = wid >> 7, wd = wid & 127;
    const int* src = adj + (size_t)row * NN + wd * 32;
    int4 v[8];
#pragma unroll
    for (int s = 0; s < 8; ++s) v[s] = *(const int4*)&src[s * 4];
    unsigned int bits = 0;
#pragma unroll
    for (int s = 0; s < 8; ++s) {
      bits |= (v[s].x ? 1u : 0u) << (s * 4 + 0);
      bits |= (v[s].y ? 1u : 0u) << (s * 4 + 1);
      bits |= (v[s].z ? 1u : 0u) << (s * 4 + 2);
      bits |= (v[s].w ? 1u : 0u) << (s * 4 + 3);
    }
    adjb[(size_t)row * NW32 + wd] = bits;
    return;
  }

  // ---- GEMM path ----
  const int r0 = bx * GROWS;
#pragma unroll
  for (int idx = t; idx < GROWS * FIN / 4; idx += 256) {
    const int r = idx >> 6, c4 = idx & 63;
    *(float4*)&hs[r][c4 * 4] =
        *(const float4*)&h[(size_t)(r0 + r) * FIN + c4 * 4];
  }
  __syncthreads();
  const int c = t;
  float acc[GROWS];
#pragma unroll
  for (int r = 0; r < GROWS; ++r) acc[r] = 0.f;
  for (int k = 0; k < FIN; k += 4) {
    const float w0 = W[(size_t)(k + 0) * CC + c];
    const float w1 = W[(size_t)(k + 1) * CC + c];
    const float w2 = W[(size_t)(k + 2) * CC + c];
    const float w3 = W[(size_t)(k + 3) * CC + c];
#pragma unroll
    for (int r = 0; r < GROWS; ++r) {
      const float4 hv = *(const float4*)&hs[r][k];
      acc[r] += hv.x * w0 + hv.y * w1 + hv.z * w2 + hv.w * w3;
    }
  }
  const int f = c & 31, hh = c >> 5;
  const float aS = a[f], aD = a[32 + f];
  unsigned short gu[GROWS];
#pragma unroll
  for (int r = 0; r < GROWS; ++r) {
    float ps = acc[r] * aS, pd = acc[r] * aD;
#pragma unroll
    for (int m = 1; m < 32; m <<= 1) {
      ps += __shfl_xor(ps, m, 64);
      pd += __shfl_xor(pd, m, 64);
    }
    if (f == 0) {
      const int n = r0 + r;
      spack[(size_t)hh * NN + n] =
          make_float4(__expf(ps), __expf(0.2f * ps), 0.f, 0.f);
      float* dc = dtc + ((size_t)hh * (NN / 32) + (n >> 5)) * 64 + (n & 31);
      dc[0] = __expf(pd);
      dc[32] = __expf(0.2f * pd);
    }
    gu[r] = bf16rn(acc[r]);
  }
  uint4 gv;
  gv.x = (unsigned)gu[0] | ((unsigned)gu[1] << 16);
  gv.y = (unsigned)gu[2] | ((unsigned)gu[3] << 16);
  gv.z = (unsigned)gu[4] | ((unsigned)gu[5] << 16);
  gv.w = (unsigned)gu[6] | ((unsigned)gu[7] << 16);
  const int jc = r0 >> 5, qq = (r0 >> 3) & 3;
  const int p = qq ^ ((c >> 1) & 3);
  *(uint4*)(gTs + ((size_t)jc * 1024 + c * 4 + p) * 8) = gv;
}

// ---------------- K2: in-block j-split, barrier-pipelined, tree-reduce -----
// Block = 32 i x 1 head x FULL 4096 j. 4 waves, wave w owns j-quarter
// [w*1024, w*1024+1024) in 16 rounds of 64 j. Wave-private LDS double-buffer
// staged via global_load_lds; ONE __syncthreads per round (fences gl_lds ->
// ds_read without sched_barrier order-pinning). dt/adj in A/B register sets
// (static names, hand-unrolled 2-round body). LDS tree-reduce epilogue.
// e^leaky(ss+sd) = max(e^ss*e^sd, e^{0.2ss}*e^{0.2sd})  (exact identity).
__global__ __launch_bounds__(256, 3) void k_attn(
    const unsigned int* __restrict__ adjb, const unsigned short* __restrict__ gTs,
    const float4* __restrict__ spack, const float* __restrict__ dtc,
    float* __restrict__ out) {
  __shared__ unsigned short gt_lds[4][2][2048];  // 32 KB: per-wave dbuf 4KB
  __shared__ float red[2][2][3][4][64];          // 12 KB reduce scratch

  const int lane = threadIdx.x & 63;
  const int w = threadIdx.x >> 6;
  const int il = lane & 15, q = lane >> 4;
  const int bx = blockIdx.x;
  const int hh = bx & 7;   // head -> XCD-pinned via %8 round-robin
  const int ib = bx >> 3;
  const int i0 = ib * 32;

  // hoisted i-side scalars
  float e1v[2], e2v[2];
#pragma unroll
  for (int it = 0; it < 2; ++it) {
    const float4 v = spack[(size_t)hh * NN + i0 + it * 16 + il];
    e1v[it] = v.x; e2v[it] = v.y;
  }

  f32x4 acc[2][2];
  f32x4 lac[2];
#pragma unroll
  for (int it = 0; it < 2; ++it) {
#pragma unroll
    for (int r = 0; r < 4; ++r) lac[it][r] = 0.f;
#pragma unroll
    for (int ft = 0; ft < 2; ++ft)
#pragma unroll
      for (int r = 0; r < 4; ++r) acc[it][ft][r] = 0.f;
  }

  const short8 ones = {(short)0x3F80, (short)0x3F80, (short)0x3F80,
                       (short)0x3F80, (short)0x3F80, (short)0x3F80,
                       (short)0x3F80, (short)0x3F80};

  const unsigned long long* abr0 =
      (const unsigned long long*)(adjb + (size_t)(i0 + il) * NW32) + w * 16;
  const unsigned long long* abr1 =
      (const unsigned long long*)(adjb + (size_t)(i0 + 16 + il) * NW32) +
      w * 16;
  const float* dbase = dtc + ((size_t)hh * (NN / 32) + w * 32) * 64;
  const int sh = q * 8;
  const int u0 = il * 4 + (q ^ ((il >> 1) & 3));  // swizzled B-frag unit

  // stage one 64-j round (2 chunks of 32 j) into wave-private buffer
  auto stage = [&](int buf, int rr) {
    const unsigned short* src =
        gTs + (((size_t)(w * 32 + rr * 2)) * 1024 + hh * 128) * 8;
    char* dst = (char*)&gt_lds[w][buf][0];
    gl_lds16(src + (size_t)lane * 8, dst);
    gl_lds16(src + (size_t)(64 + lane) * 8, dst + 1024);
    gl_lds16(src + (size_t)(1024 + lane) * 8, dst + 2048);
    gl_lds16(src + (size_t)(1024 + 64 + lane) * 8, dst + 3072);
  };

  // A/B register prefetch sets (static names — rule #20)
  unsigned long long Ab0, Ab1, Bb0, Bb1;
  float4 Ad0, Ad1, Ad2, Ad3, Ad4, Ad5, Ad6, Ad7;
  float4 Bd0, Bd1, Bd2, Bd3, Bd4, Bd5, Bd6, Bd7;

#define ISSUE_REGS(P, rr)                                  \
  {                                                        \
    P##b0 = abr0[rr]; P##b1 = abr1[rr];                    \
    const float* dp_ = dbase + (size_t)(rr) * 128;         \
    P##d0 = *(const float4*)(dp_ + q * 8);                 \
    P##d1 = *(const float4*)(dp_ + q * 8 + 4);             \
    P##d2 = *(const float4*)(dp_ + 32 + q * 8);            \
    P##d3 = *(const float4*)(dp_ + 32 + q * 8 + 4);        \
    P##d4 = *(const float4*)(dp_ + 64 + q * 8);            \
    P##d5 = *(const float4*)(dp_ + 64 + q * 8 + 4);        \
    P##d6 = *(const float4*)(dp_ + 96 + q * 8);            \
    P##d7 = *(const float4*)(dp_ + 96 + q * 8 + 4);        \
  }

#define COMPUTE(P)                                                          \
  {                                                                         \
    _Pragma("unroll") for (int sub = 0; sub < 2; ++sub) {                   \
      const unsigned int bits0 = (unsigned int)(P##b0 >> (sub * 32));       \
      const unsigned int bits1 = (unsigned int)(P##b1 >> (sub * 32));       \
      float e1j[8], e2j[8];                                                 \
      if (sub == 0) {                                                       \
        *(float4*)&e1j[0] = P##d0; *(float4*)&e1j[4] = P##d1;               \
        *(float4*)&e2j[0] = P##d2; *(float4*)&e2j[4] = P##d3;               \
      } else {                                                              \
        *(float4*)&e1j[0] = P##d4; *(float4*)&e1j[4] = P##d5;               \
        *(float4*)&e2j[0] = P##d6; *(float4*)&e2j[4] = P##d7;               \
      }                                                                     \
      const unsigned short* gb = &gt_lds[w][cur][sub * 1024];               \
      const short8 b0 = *(const short8*)&gb[u0 * 8];                        \
      const short8 b1 = *(const short8*)&gb[(u0 + 64) * 8];                 \
      _Pragma("unroll") for (int it = 0; it < 2; ++it) {                    \
        const unsigned int bits = it ? bits1 : bits0;                       \
        const float ei1 = e1v[it], ei2 = e2v[it];                           \
        float wv[8];                                                        \
        _Pragma("unroll") for (int e = 0; e < 8; ++e)                       \
            wv[e] = ((bits >> (sh + e)) & 1u)                               \
                        ? fmaxf(ei1 * e1j[e], ei2 * e2j[e])                 \
                        : 0.f;                                              \
        u32x4 uu;                                                           \
        _Pragma("unroll") for (int m = 0; m < 4; ++m)                       \
            uu[m] = cvtpk_bf16(wv[2 * m], wv[2 * m + 1]);                   \
        const short8 afr = __builtin_bit_cast(short8, uu);                  \
        acc[it][0] = __builtin_amdgcn_mfma_f32_16x16x32_bf16(               \
            afr, b0, acc[it][0], 0, 0, 0);                                  \
        acc[it][1] = __builtin_amdgcn_mfma_f32_16x16x32_bf16(               \
            afr, b1, acc[it][1], 0, 0, 0);                                  \
        lac[it] = __builtin_amdgcn_mfma_f32_16x16x32_bf16(                  \
            afr, ones, lac[it], 0, 0, 0);                                   \
      }                                                                     \
    }                                                                       \
  }

  // prologue: round 0 staged + regs in set A
  stage(0, 0);
  ISSUE_REGS(A, 0);
  __syncthreads();
  int cur = 0;

#pragma unroll 1
  for (int r2 = 0; r2 < 8; ++r2) {
    const int r = r2 * 2;
    if (r + 1 < 16) { stage(cur ^ 1, r + 1); ISSUE_REGS(B, r + 1); }
    COMPUTE(A);
    __syncthreads();
    cur ^= 1;
    if (r + 2 < 16) { stage(cur ^ 1, r + 2); ISSUE_REGS(A, r + 2); }
    COMPUTE(B);
    __syncthreads();
    cur ^= 1;
  }
#undef ISSUE_REGS
#undef COMPUTE

  // ---- cross-wave tree reduction (j-quarters -> full j sum) ----
  if (w >= 2) {
    const int s = w - 2;
#pragma unroll
    for (int it = 0; it < 2; ++it)
#pragma unroll
      for (int r = 0; r < 4; ++r) {
        red[s][it][0][r][lane] = acc[it][0][r];
        red[s][it][1][r][lane] = acc[it][1][r];
        red[s][it][2][r][lane] = lac[it][r];
      }
  }
  __syncthreads();
  if (w < 2) {
#pragma unroll
    for (int it = 0; it < 2; ++it)
#pragma unroll
      for (int r = 0; r < 4; ++r) {
        acc[it][0][r] += red[w][it][0][r][lane];
        acc[it][1][r] += red[w][it][1][r][lane];
        lac[it][r] += red[w][it][2][r][lane];
      }
  }
  __syncthreads();
  if (w == 1) {
#pragma unroll
    for (int it = 0; it < 2; ++it)
#pragma unroll
      for (int r = 0; r < 4; ++r) {
        red[0][it][0][r][lane] = acc[it][0][r];
        red[0][it][1][r][lane] = acc[it][1][r];
        red[0][it][2][r][lane] = lac[it][r];
      }
  }
  __syncthreads();
  if (w == 0) {
#pragma unroll
    for (int it = 0; it < 2; ++it)
#pragma unroll
      for (int r = 0; r < 4; ++r) {
        const float a0 = acc[it][0][r] + red[0][it][0][r][lane];
        const float a1 = acc[it][1][r] + red[0][it][1][r][lane];
        const float lsum = lac[it][r] + red[0][it][2][r][lane];
        const float inv = 1.f / lsum;
        const size_t irow = i0 + it * 16 + q * 4 + r;
        out[irow * CC + hh * 32 + il] = a0 * inv;
        out[irow * CC + hh * 32 + 16 + il] = a1 * inv;
      }
  }
}

extern "C" void kernel_launch(void* const* d_in, const int* in_sizes, int n_in,
                              void* d_out, int out_size, void* d_ws,
                              size_t ws_size, hipStream_t stream) {
  (void)in_sizes; (void)n_in; (void)out_size; (void)ws_size;
  const float* h = (const float*)d_in[0];
  const int* adj = (const int*)d_in[1];
  const float* W = (const float*)d_in[2];
  const float* a = (const float*)d_in[3];
  float* out = (float*)d_out;
  char* ws = (char*)d_ws;

  unsigned short* gTs = (unsigned short*)ws;               // 2 MB (swizzled)
  float4* spack = (float4*)(ws + (size_t)NN * CC * 2);     // 512 KB
  float* dtc = (float*)(spack + (size_t)NH * NN);          // 256 KB
  unsigned int* adjb =
      (unsigned int*)(dtc + (size_t)NH * (NN / 32) * 64);  // 2 MB

  k_gemm<<<GEMM_BLKS + BP_BLKS, 256, 0, stream>>>(h, W, a, adj, adjb, gTs,
                                                  spack, dtc);
  k_attn<<<(NN / 32) * NH, 256, 0, stream>>>(adjb, gTs, spack, dtc, out);
}